// Round 1
// baseline (67.346 us; speedup 1.0000x reference)
//
#include <hip/hip_runtime.h>
#include <math.h>

#define RCR 5.2f
#define RCA 3.5f
#define ETA_R 16.0f
#define ETA_A 8.0f
#define PI_F 3.14159265358979323846f
#define MAXN 256   // n = 200 for this problem; arrays sized to 256

// One block per atom i. 256 threads.
__global__ __launch_bounds__(256) void aev_kernel(const float* __restrict__ coords,
                                                  float* __restrict__ out, int n) {
    const int i = blockIdx.x;
    const int tid = threadIdx.x;

    __shared__ float sx[MAXN], sy[MAXN], sz[MAXN];
    // compacted neighbor list (d <= RCA, j != i)
    __shared__ float nd[MAXN], nfca[MAXN], nux[MAXN], nuy[MAXN], nuz[MAXN];
    __shared__ int nb_cnt;
    __shared__ float s_rad[16];
    __shared__ float s_ang[32];

    for (int j = tid; j < n; j += blockDim.x) {
        sx[j] = coords[3 * j + 0];
        sy[j] = coords[3 * j + 1];
        sz[j] = coords[3 * j + 2];
    }
    if (tid == 0) nb_cnt = 0;
    if (tid < 16) s_rad[tid] = 0.0f;
    if (tid < 32) s_ang[tid] = 0.0f;
    __syncthreads();

    const float xi = sx[i], yi = sy[i], zi = sz[i];

    // ---- pass over j: radial accumulation + angular neighbor-list build
    float racc[16];
#pragma unroll
    for (int r = 0; r < 16; r++) racc[r] = 0.0f;

    for (int j = tid; j < n; j += blockDim.x) {
        if (j == i) continue;
        const float dx = xi - sx[j];
        const float dy = yi - sy[j];
        const float dz = zi - sz[j];
        const float d = sqrtf(dx * dx + dy * dy + dz * dz);
        if (d <= RCR) {
            const float fcr = 0.5f * cosf(PI_F * d / RCR) + 0.5f;
#pragma unroll
            for (int r = 0; r < 16; r++) {
                const float t = d - (0.9f + 0.26875f * (float)r);  // linspace(0.9, 4.93125, 16)
                racc[r] += expf(-ETA_R * t * t) * fcr;
            }
        }
        if (d <= RCA) {
            const int slot = atomicAdd(&nb_cnt, 1);
            const float inv = 1.0f / d;
            nd[slot] = d;
            nfca[slot] = 0.5f * cosf(PI_F * d / RCA) + 0.5f;
            nux[slot] = dx * inv;
            nuy[slot] = dy * inv;
            nuz[slot] = dz * inv;
        }
    }

    // reduce radial: wave64 tree + one shared atomic per wave per channel
#pragma unroll
    for (int r = 0; r < 16; r++) {
        float v = racc[r];
        for (int off = 32; off > 0; off >>= 1) v += __shfl_down(v, off);
        if ((tid & 63) == 0) atomicAdd(&s_rad[r], v);
    }
    __syncthreads();

    const int m = nb_cnt;

    // ---- angular: ordered pairs (j,k), j != k, over the m neighbors
    // ShfZ constants; cos(theta - ShfZ) = ct*cos(ShfZ) + st*sin(ShfZ),
    // with ct = 0.95*cosT (theta = acos(0.95*cosT)), st = sqrt(1-ct^2) >= 0.
    const float shfZ[8] = {0.19634954f, 0.58904862f, 0.9817477f, 1.3744468f,
                           1.7671459f, 2.1598449f, 2.552544f, 2.9452431f};
    float cZ[8], sZ[8];
#pragma unroll
    for (int z = 0; z < 8; z++) {
        cZ[z] = cosf(shfZ[z]);
        sZ[z] = sinf(shfZ[z]);
    }

    float aacc[32];
#pragma unroll
    for (int c = 0; c < 32; c++) aacc[c] = 0.0f;

    const int npairs = m * m;
    for (int p = tid; p < npairs; p += blockDim.x) {
        const int j = p / m;
        const int k = p - j * m;
        if (j == k) continue;
        const float ct = 0.95f * (nux[j] * nux[k] + nuy[j] * nuy[k] + nuz[j] * nuz[k]);
        const float st = sqrtf(fmaxf(0.0f, 1.0f - ct * ct));
        const float davg = 0.5f * (nd[j] + nd[k]);
        const float fcp = nfca[j] * nfca[k];

        float f2[4];
#pragma unroll
        for (int a = 0; a < 4; a++) {
            const float t = davg - (0.9f + 0.65f * (float)a);  // ShfA = {0.9,1.55,2.2,2.85}
            f2[a] = expf(-ETA_A * t * t) * fcp;
        }
#pragma unroll
        for (int z = 0; z < 8; z++) {
            const float x = (1.0f + ct * cZ[z] + st * sZ[z]) * 0.5f;  // in [0,1]
            float t = x * x;   // ^2
            t = t * t;         // ^4
            t = t * t;         // ^8
            t = t * t;         // ^16
            t = t * t;         // ^32
#pragma unroll
            for (int a = 0; a < 4; a++) aacc[a * 8 + z] += f2[a] * t;
        }
    }

#pragma unroll
    for (int c = 0; c < 32; c++) {
        float v = aacc[c];
        for (int off = 32; off > 0; off >>= 1) v += __shfl_down(v, off);
        if ((tid & 63) == 0) atomicAdd(&s_ang[c], v);
    }
    __syncthreads();

    // ---- write full 384-wide row (zeros for non-species-0 blocks)
    float* row = out + (size_t)i * 384;
    for (int c = tid; c < 384; c += blockDim.x) {
        float v = 0.0f;
        if (c < 16) v = 0.25f * s_rad[c];
        else if (c >= 64 && c < 96) v = s_ang[c - 64];
        row[c] = v;
    }
}

extern "C" void kernel_launch(void* const* d_in, const int* in_sizes, int n_in,
                              void* d_out, int out_size, void* d_ws, size_t ws_size,
                              hipStream_t stream) {
    const float* coords = (const float*)d_in[0];
    float* out = (float*)d_out;
    const int n = in_sizes[0] / 3;  // 200
    aev_kernel<<<n, 256, 0, stream>>>(coords, out, n);
}

// Round 3
// 58.442 us; speedup vs baseline: 1.1524x; 1.1524x over previous
//
#include <hip/hip_runtime.h>
#include <math.h>

#define RCR 5.2f
#define RCA 3.5f
#define ETA_R 16.0f
#define ETA_A 8.0f
#define PI_F 3.14159265358979323846f
#define MAXN 256   // n = 200 for this problem

// ---- wave64 sum via DPP (VALU pipe, no LDS traffic) ----
// ctrl/row_mask must be integer constant expressions -> template params.
template <int CTRL, int ROW_MASK>
__device__ __forceinline__ float dpp_add(float v) {
    int s = __builtin_amdgcn_update_dpp(0, __float_as_int(v), CTRL, ROW_MASK, 0xf, true);
    return v + __int_as_float(s);
}
__device__ __forceinline__ float wave64_sum(float v) {
    v = dpp_add<0x111, 0xf>(v);  // row_shr:1
    v = dpp_add<0x112, 0xf>(v);  // row_shr:2
    v = dpp_add<0x114, 0xf>(v);  // row_shr:4
    v = dpp_add<0x118, 0xf>(v);  // row_shr:8  -> lane15 of each row = row sum
    v = dpp_add<0x142, 0xa>(v);  // row_bcast:15 into rows 1,3
    v = dpp_add<0x143, 0xc>(v);  // row_bcast:31 into rows 2,3 -> lane63 = total
    return v;
}

// One block per atom i, 256 threads (4 waves). n <= 256 assumed (n=200 here).
__global__ __launch_bounds__(256) void aev_kernel(const float* __restrict__ coords,
                                                  float* __restrict__ out, int n) {
    const int i = blockIdx.x;
    const int tid = threadIdx.x;
    const int lane = tid & 63;
    const int wv = tid >> 6;

    __shared__ float sx[MAXN], sy[MAXN], sz[MAXN];
    __shared__ float4 njd[MAXN];   // compacted neighbors: (ux, uy, uz, d)
    __shared__ float nfc[MAXN];    // fc_a per neighbor
    __shared__ int s_wcnt[4];
    __shared__ float s_rad[16];
    __shared__ float s_ang[32];

    if (tid < n) {
        sx[tid] = coords[3 * tid + 0];
        sy[tid] = coords[3 * tid + 1];
        sz[tid] = coords[3 * tid + 2];
    }
    if (tid < 16) s_rad[tid] = 0.0f;
    if (tid < 32) s_ang[tid] = 0.0f;
    __syncthreads();

    const float xi = sx[i], yi = sy[i], zi = sz[i];

    // ---- one j per thread: distance, radial contribution, neighbor predicate
    const int j = tid;
    const bool valid = (j < n) && (j != i);
    float dx = 0.f, dy = 0.f, dz = 0.f, d = 1.0e9f;
    if (valid) {
        dx = xi - sx[j]; dy = yi - sy[j]; dz = zi - sz[j];
        d = sqrtf(dx * dx + dy * dy + dz * dz);
    }
    const float fcr = (d <= RCR) ? (0.5f * __cosf(d * (PI_F / RCR)) + 0.5f) : 0.0f;
    float racc[16];
#pragma unroll
    for (int r = 0; r < 16; r++) {
        const float t = d - (0.9f + 0.26875f * (float)r);   // linspace(0.9,4.93125,16)
        racc[r] = fcr * __expf(-ETA_R * t * t);             // fcr==0 kills invalid lanes
    }

    // ---- ballot-based compaction of RCA neighbors (deterministic, no atomics)
    const bool pred = valid && (d <= RCA);
    const unsigned long long bmask = __ballot(pred);
    if (lane == 0) s_wcnt[wv] = __popcll(bmask);
    __syncthreads();
    int base = 0;
#pragma unroll
    for (int w = 0; w < 4; w++) if (w < wv) base += s_wcnt[w];
    const int m = s_wcnt[0] + s_wcnt[1] + s_wcnt[2] + s_wcnt[3];
    if (pred) {
        const int slot = base + __popcll(bmask & ((1ULL << lane) - 1ULL));
        const float inv = 1.0f / d;
        njd[slot] = make_float4(dx * inv, dy * inv, dz * inv, d);
        nfc[slot] = 0.5f * __cosf(d * (PI_F / RCA)) + 0.5f;
    }

    // ---- radial reduce: DPP wave sum + one shared atomic per wave per channel
#pragma unroll
    for (int r = 0; r < 16; r++) {
        const float v = wave64_sum(racc[r]);
        if (lane == 63) atomicAdd(&s_rad[r], v);
    }
    __syncthreads();   // neighbor list + radial complete

    // ---- angular: triangular (j<k) pairs, final x2 (f1,f2 symmetric in j,k)
    // cos(theta - ShfZ) = ct*cos(ShfZ) + st*sin(ShfZ); ct = 0.95*cosT, st = sqrt(1-ct^2)
    const float cZ[8] = { 0.98078528f,  0.83146961f,  0.55557023f,  0.19509032f,
                         -0.19509032f, -0.55557023f, -0.83146961f, -0.98078528f};
    const float sZ[8] = { 0.19509032f,  0.55557023f,  0.83146961f,  0.98078528f,
                          0.98078528f,  0.83146961f,  0.55557023f,  0.19509032f};
    float aacc[32];
#pragma unroll
    for (int c = 0; c < 32; c++) aacc[c] = 0.0f;

    const int T = m * (m - 1) / 2;
    for (int p = tid; p < T; p += 256) {
        // decode triangular index: p = jj*(jj-1)/2 + kk, 0 <= kk < jj < m
        int jj = (int)((1.0f + sqrtf(8.0f * (float)p + 1.0f)) * 0.5f);
        while (jj * (jj - 1) / 2 > p) jj--;
        while ((jj + 1) * jj / 2 <= p) jj++;
        const int kk = p - jj * (jj - 1) / 2;

        const float4 a = njd[jj];
        const float4 b = njd[kk];
        const float ct = 0.95f * (a.x * b.x + a.y * b.y + a.z * b.z);
        const float st = sqrtf(fmaxf(0.0f, 1.0f - ct * ct));
        const float davg = 0.5f * (a.w + b.w);
        const float fcp = nfc[jj] * nfc[kk];

        float f2[4];
#pragma unroll
        for (int aa = 0; aa < 4; aa++) {
            const float t = davg - (0.9f + 0.65f * (float)aa);  // ShfA
            f2[aa] = fcp * __expf(-ETA_A * t * t);
        }
#pragma unroll
        for (int z = 0; z < 8; z++) {
            const float x = fmaf(ct, cZ[z], fmaf(st, sZ[z], 1.0f)) * 0.5f;  // [0,1]
            float t2 = x * x; t2 *= t2; t2 *= t2; t2 *= t2; t2 *= t2;       // x^32
#pragma unroll
            for (int aa = 0; aa < 4; aa++)
                aacc[aa * 8 + z] = fmaf(f2[aa], t2, aacc[aa * 8 + z]);
        }
    }

#pragma unroll
    for (int c = 0; c < 32; c++) {
        const float v = wave64_sum(aacc[c]);
        if (lane == 63) atomicAdd(&s_ang[c], v);
    }
    __syncthreads();

    // ---- write full 384-wide row (zeros outside species-0 blocks)
    float* row = out + (size_t)i * 384;
    for (int c = tid; c < 384; c += 256) {
        float v = 0.0f;
        if (c < 16) v = 0.25f * s_rad[c];
        else if (c >= 64 && c < 96) v = 2.0f * s_ang[c - 64];  // ordered = 2 * (j<k)
        row[c] = v;
    }
}

extern "C" void kernel_launch(void* const* d_in, const int* in_sizes, int n_in,
                              void* d_out, int out_size, void* d_ws, size_t ws_size,
                              hipStream_t stream) {
    const float* coords = (const float*)d_in[0];
    float* out = (float*)d_out;
    const int n = in_sizes[0] / 3;  // 200
    aev_kernel<<<n, 256, 0, stream>>>(coords, out, n);
}

// Round 4
// 56.019 us; speedup vs baseline: 1.2022x; 1.0433x over previous
//
#include <hip/hip_runtime.h>
#include <math.h>

#define RCR 5.2f
#define RCA 3.5f
#define ETA_R 16.0f
#define ETA_A 8.0f
#define PI_F 3.14159265358979323846f
#define MAXN 256   // n = 200 for this problem

// ---- wave64 sum via DPP (VALU pipe, no LDS traffic); total lands in lane 63.
template <int CTRL, int ROW_MASK>
__device__ __forceinline__ float dpp_add(float v) {
    int s = __builtin_amdgcn_update_dpp(0, __float_as_int(v), CTRL, ROW_MASK, 0xf, true);
    return v + __int_as_float(s);
}
__device__ __forceinline__ float wave64_sum(float v) {
    v = dpp_add<0x111, 0xf>(v);  // row_shr:1
    v = dpp_add<0x112, 0xf>(v);  // row_shr:2
    v = dpp_add<0x114, 0xf>(v);  // row_shr:4
    v = dpp_add<0x118, 0xf>(v);  // row_shr:8  -> lane15 of each row = row sum
    v = dpp_add<0x142, 0xa>(v);  // row_bcast:15 into rows 1,3
    v = dpp_add<0x143, 0xc>(v);  // row_bcast:31 into rows 2,3 -> lane63 = total
    return v;
}

// One block per atom i, 256 threads (4 waves). n <= 256 assumed (n=200 here).
__global__ __launch_bounds__(256) void aev_kernel(const float* __restrict__ coords,
                                                  float* __restrict__ out, int n) {
    const int i = blockIdx.x;
    const int tid = threadIdx.x;
    const int lane = tid & 63;
    const int wv = tid >> 6;

    __shared__ __align__(16) float scoord[3 * MAXN];  // x,y,z interleaved
    __shared__ float4 njd[MAXN];   // compacted neighbors: (ux, uy, uz, d)
    __shared__ float nfc[MAXN];    // fc_a per neighbor
    __shared__ int s_wcnt[4];
    __shared__ float s_radw[4][16];  // per-wave radial partials
    __shared__ float s_angw[4][32];  // per-wave angular partials

    // ---- vectorized coord staging: 3n floats as float4 chunks + scalar tail
    {
        const int total = 3 * n;
        const int n4 = total >> 2;              // full float4 count
        if (tid < n4) {
            ((float4*)scoord)[tid] = ((const float4*)coords)[tid];
        } else if (tid == n4) {
            for (int c = n4 * 4; c < total; c++) scoord[c] = coords[c];
        }
    }
    __syncthreads();

    const float xi = scoord[3 * i + 0], yi = scoord[3 * i + 1], zi = scoord[3 * i + 2];

    // ---- one j per thread: distance, radial contribution, neighbor predicate
    const int j = tid;
    const bool valid = (j < n) && (j != i);
    float dx = 0.f, dy = 0.f, dz = 0.f, d = 1.0e9f;
    if (valid) {
        dx = xi - scoord[3 * j + 0];
        dy = yi - scoord[3 * j + 1];
        dz = zi - scoord[3 * j + 2];
        d = sqrtf(dx * dx + dy * dy + dz * dz);
    }
    const float fcr = (d <= RCR) ? (0.5f * __cosf(d * (PI_F / RCR)) + 0.5f) : 0.0f;
    float racc[16];
#pragma unroll
    for (int r = 0; r < 16; r++) {
        const float t = d - (0.9f + 0.26875f * (float)r);   // linspace(0.9,4.93125,16)
        racc[r] = fcr * __expf(-ETA_R * t * t);             // fcr==0 kills invalid lanes
    }

    // ---- ballot-based compaction of RCA neighbors (deterministic, no atomics)
    const bool pred = valid && (d <= RCA);
    const unsigned long long bmask = __ballot(pred);
    if (lane == 0) s_wcnt[wv] = __popcll(bmask);
    __syncthreads();
    int base = 0;
#pragma unroll
    for (int w = 0; w < 4; w++) if (w < wv) base += s_wcnt[w];
    const int m = s_wcnt[0] + s_wcnt[1] + s_wcnt[2] + s_wcnt[3];
    if (pred) {
        const int slot = base + __popcll(bmask & ((1ULL << lane) - 1ULL));
        const float inv = 1.0f / d;
        njd[slot] = make_float4(dx * inv, dy * inv, dz * inv, d);
        nfc[slot] = 0.5f * __cosf(d * (PI_F / RCA)) + 0.5f;
    }

    // ---- radial reduce: DPP wave sum -> per-wave LDS partial (no atomics)
#pragma unroll
    for (int r = 0; r < 16; r++) {
        const float v = wave64_sum(racc[r]);
        if (lane == 63) s_radw[wv][r] = v;
    }
    __syncthreads();   // neighbor list + radial partials complete

    // ---- angular: triangular (j<k) pairs, final x2 (f1,f2 symmetric in j,k)
    // cos(theta - ShfZ) = ct*cos(ShfZ) + st*sin(ShfZ); ct = 0.95*cosT, st = sqrt(1-ct^2)
    const float cZ[8] = { 0.98078528f,  0.83146961f,  0.55557023f,  0.19509032f,
                         -0.19509032f, -0.55557023f, -0.83146961f, -0.98078528f};
    const float sZ[8] = { 0.19509032f,  0.55557023f,  0.83146961f,  0.98078528f,
                          0.98078528f,  0.83146961f,  0.55557023f,  0.19509032f};
    float aacc[32];
#pragma unroll
    for (int c = 0; c < 32; c++) aacc[c] = 0.0f;

    const int T = m * (m - 1) / 2;
    for (int p = tid; p < T; p += 256) {
        // decode triangular index: p = jj*(jj-1)/2 + kk, 0 <= kk < jj < m
        int jj = (int)((1.0f + sqrtf(8.0f * (float)p + 1.0f)) * 0.5f);
        while (jj * (jj - 1) / 2 > p) jj--;
        while ((jj + 1) * jj / 2 <= p) jj++;
        const int kk = p - jj * (jj - 1) / 2;

        const float4 a = njd[jj];
        const float4 b = njd[kk];
        const float ct = 0.95f * (a.x * b.x + a.y * b.y + a.z * b.z);
        const float st = sqrtf(fmaxf(0.0f, 1.0f - ct * ct));
        const float davg = 0.5f * (a.w + b.w);
        const float fcp = nfc[jj] * nfc[kk];

        // f2[a] = fcp*exp(-8*(davg-sa)^2), sa=0.9+0.65a, via exp recurrence:
        // t_{a+1} = t_a * u, u *= w, w = exp(-2*8*0.65^2)
        const float dv0 = davg - 0.9f;
        float t0 = __expf(-ETA_A * dv0 * dv0);
        float u = __expf(fmaf(10.4f, davg, -12.74f));   // exp(2*8*0.65*davg - 8*0.65*(2*0.9+0.65))
        const float w = 0.00115743f;                    // exp(-6.76)
        float f2[4];
        f2[0] = fcp * t0;
        t0 *= u; u *= w; f2[1] = fcp * t0;
        t0 *= u; u *= w; f2[2] = fcp * t0;
        t0 *= u;         f2[3] = fcp * t0;

#pragma unroll
        for (int z = 0; z < 8; z++) {
            const float x = fmaf(ct, cZ[z], fmaf(st, sZ[z], 1.0f)) * 0.5f;  // [0,1]
            float t2 = x * x; t2 *= t2; t2 *= t2; t2 *= t2; t2 *= t2;       // x^32
#pragma unroll
            for (int aa = 0; aa < 4; aa++)
                aacc[aa * 8 + z] = fmaf(f2[aa], t2, aacc[aa * 8 + z]);
        }
    }

#pragma unroll
    for (int c = 0; c < 32; c++) {
        const float v = wave64_sum(aacc[c]);
        if (lane == 63) s_angw[wv][c] = v;
    }
    __syncthreads();

    // ---- write full 384-wide row as float4 (96 per row; regions are x4-aligned)
    float4* row4 = (float4*)(out + (size_t)i * 384);
    for (int c4 = tid; c4 < 96; c4 += 256) {
        float4 v = make_float4(0.f, 0.f, 0.f, 0.f);
        if (c4 < 4) {           // radial cols [0,16)
            const int c = 4 * c4;
            float* p = &v.x;
#pragma unroll
            for (int q = 0; q < 4; q++)
                p[q] = 0.25f * (s_radw[0][c + q] + s_radw[1][c + q] +
                                s_radw[2][c + q] + s_radw[3][c + q]);
        } else if (c4 >= 16 && c4 < 24) {   // angular cols [64,96)
            const int c = 4 * (c4 - 16);
            float* p = &v.x;
#pragma unroll
            for (int q = 0; q < 4; q++)
                p[q] = 2.0f * (s_angw[0][c + q] + s_angw[1][c + q] +
                               s_angw[2][c + q] + s_angw[3][c + q]);
        }
        row4[c4] = v;
    }
}

extern "C" void kernel_launch(void* const* d_in, const int* in_sizes, int n_in,
                              void* d_out, int out_size, void* d_ws, size_t ws_size,
                              hipStream_t stream) {
    const float* coords = (const float*)d_in[0];
    float* out = (float*)d_out;
    const int n = in_sizes[0] / 3;  // 200
    aev_kernel<<<n, 256, 0, stream>>>(coords, out, n);
}